// Round 1
// baseline (259.302 us; speedup 1.0000x reference)
//
#include <hip/hip_runtime.h>
#include <float.h>

// Problem constants (fixed by reference): B=32 L=1024 D=128 K=1024
#define NTOK 32768
#define DDIM 128
#define KCODES 1024
#define TT 128    // tokens per block
#define KC 128    // codes per K-chunk
#define NCHUNK (KCODES / KC)

// Optimization barrier: prevents fma-contraction / reassociation across it,
// so we can replicate numpy's exact fp32 rounding sequence.
__device__ __forceinline__ float nofuse(float x) { asm volatile("" : "+v"(x)); return x; }

// numpy pairwise_sum for n=128 (its n<=PW_BLOCKSIZE path): 8 accumulators,
// r[j] = a[j] + a[8+j] + ... + a[120+j] (sequential), then
// ((r0+r1)+(r2+r3)) + ((r4+r5)+(r6+r7)). Squares rounded BEFORE adding
// (numpy computes z**2 elementwise first) — nofuse blocks fma fusion.
__global__ void rownorm_np(const float* __restrict__ a, float* __restrict__ out, int nrows) {
    int row = blockIdx.x * blockDim.x + threadIdx.x;
    if (row >= nrows) return;
    const float* p = a + (size_t)row * DDIM;
    float r[8];
    #pragma unroll
    for (int j = 0; j < 8; ++j) { float v = p[j]; r[j] = nofuse(v * v); }
    #pragma unroll
    for (int i = 8; i < DDIM; i += 8) {
        #pragma unroll
        for (int j = 0; j < 8; ++j) {
            float v = p[i + j];
            r[j] = nofuse(r[j] + nofuse(v * v));
        }
    }
    float s01 = nofuse(r[0] + r[1]);
    float s23 = nofuse(r[2] + r[3]);
    float s45 = nofuse(r[4] + r[5]);
    float s67 = nofuse(r[6] + r[7]);
    out[row] = nofuse(nofuse(s01 + s23) + nofuse(s45 + s67));
}

// ---------------- distances + argmin ----------------
// dist(t,k) = fl( fl(zn_t + cn_k) - 2*dot(z_t,c_k) )  — numpy fp32 semantics.
// 8x8 register tile per thread: 64 FMA per 4 ds_read_b128 -> 1 B LDS per
// lane-FMA, the VALU/LDS balance point (prev 4x4 tile was 2 B/FMA -> 50% VALU).
__global__ __launch_bounds__(256, 1)
void dist_argmin(const float* __restrict__ z, const float* __restrict__ cb,
                 const float* __restrict__ cnorm,
                 int* __restrict__ idx_out, float* __restrict__ idxf_out) {
    // LDS: zt[DDIM][TT] | ct[DDIM][KC] | zn_s[TT] | cn_s[KC]   (~132 KB, 1 block/CU)
    __shared__ float smem[DDIM * TT + DDIM * KC + TT + KC];
    float* zt   = smem;                    // [d][token], pitch TT
    float* ct   = smem + DDIM * TT;        // [d][code],  pitch KC
    float* zn_s = ct + DDIM * KC;          // [TT]
    float* cn_s = zn_s + TT;               // [KC]

    const int tid = threadIdx.x;
    const int tx = tid & 15;   // code micro-col  (codes {4tx..4tx+3} U {64+4tx..})
    const int ty = tid >> 4;   // token micro-row (tokens {4ty..4ty+3} U {64+4ty..})
    const int t0 = blockIdx.x * TT;

    // ---- prefetch c-chunk 0 into registers (T14: loads fly over z staging) ----
    float4 creg[16];
    #pragma unroll
    for (int it = 0; it < 16; ++it) {
        int g  = it * 256 + tid;
        int c  = g & (KC - 1);
        int d4 = g >> 7;
        creg[it] = *(const float4*)(cb + (size_t)c * DDIM + 4 * d4);
    }
    float cnr = 0.0f;
    if (tid < KC) cnr = cnorm[tid];

    // ---- stage z-tile transposed: zt[d][t] ----
    #pragma unroll
    for (int it = 0; it < 16; ++it) {
        int g  = it * 256 + tid;
        int t  = g & (TT - 1);
        int d4 = g >> 7;
        float4 v = *(const float4*)(z + (size_t)(t0 + t) * DDIM + 4 * d4);
        zt[(4 * d4 + 0) * TT + t] = v.x;
        zt[(4 * d4 + 1) * TT + t] = v.y;
        zt[(4 * d4 + 2) * TT + t] = v.z;
        zt[(4 * d4 + 3) * TT + t] = v.w;
    }
    __syncthreads();

    // ---- fused znorm: identical numpy pairwise sequence, fed from zt column ----
    if (tid < TT) {
        const float* col = zt + tid;   // col[d*TT] == z[t0+tid][d], exact copies
        float r[8];
        #pragma unroll
        for (int j = 0; j < 8; ++j) { float v = col[j * TT]; r[j] = nofuse(v * v); }
        #pragma unroll
        for (int i = 8; i < DDIM; i += 8) {
            #pragma unroll
            for (int j = 0; j < 8; ++j) {
                float v = col[(i + j) * TT];
                r[j] = nofuse(r[j] + nofuse(v * v));
            }
        }
        float s01 = nofuse(r[0] + r[1]);
        float s23 = nofuse(r[2] + r[3]);
        float s45 = nofuse(r[4] + r[5]);
        float s67 = nofuse(r[6] + r[7]);
        zn_s[tid] = nofuse(nofuse(s01 + s23) + nofuse(s45 + s67));
    }

    float minv[8];
    int   mini[8];
    #pragma unroll
    for (int i = 0; i < 8; ++i) { minv[i] = FLT_MAX; mini[i] = 0; }

    for (int cc = 0; cc < NCHUNK; ++cc) {
        const int kc = cc * KC;
        __syncthreads();   // prev compute done reading ct (iter0: zn_s written)

        // write prefetched chunk to LDS (transposed)
        #pragma unroll
        for (int it = 0; it < 16; ++it) {
            int g  = it * 256 + tid;
            int c  = g & (KC - 1);
            int d4 = g >> 7;
            float4 v = creg[it];
            ct[(4 * d4 + 0) * KC + c] = v.x;
            ct[(4 * d4 + 1) * KC + c] = v.y;
            ct[(4 * d4 + 2) * KC + c] = v.z;
            ct[(4 * d4 + 3) * KC + c] = v.w;
        }
        if (tid < KC) cn_s[tid] = cnr;
        __syncthreads();

        // prefetch next chunk (overlaps with the 128-step FMA phase below)
        if (cc + 1 < NCHUNK) {
            #pragma unroll
            for (int it = 0; it < 16; ++it) {
                int g  = it * 256 + tid;
                int c  = g & (KC - 1);
                int d4 = g >> 7;
                creg[it] = *(const float4*)(cb + (size_t)(kc + KC + c) * DDIM + 4 * d4);
            }
            if (tid < KC) cnr = cnorm[kc + KC + tid];
        }

        float acc[8][8];
        #pragma unroll
        for (int i = 0; i < 8; ++i)
            #pragma unroll
            for (int j = 0; j < 8; ++j) acc[i][j] = 0.0f;

        #pragma unroll 4
        for (int d = 0; d < DDIM; ++d) {
            float4 a0 = *(const float4*)(zt + d * TT + 4 * ty);
            float4 a1 = *(const float4*)(zt + d * TT + 64 + 4 * ty);
            float4 b0 = *(const float4*)(ct + d * KC + 4 * tx);
            float4 b1 = *(const float4*)(ct + d * KC + 64 + 4 * tx);
            float ar[8] = {a0.x, a0.y, a0.z, a0.w, a1.x, a1.y, a1.z, a1.w};
            float br[8] = {b0.x, b0.y, b0.z, b0.w, b1.x, b1.y, b1.z, b1.w};
            #pragma unroll
            for (int i = 0; i < 8; ++i)
                #pragma unroll
                for (int j = 0; j < 8; ++j)
                    acc[i][j] = fmaf(ar[i], br[j], acc[i][j]);
        }

        #pragma unroll
        for (int j = 0; j < 8; ++j) {
            int cl = (j < 4) ? (4 * tx + j) : (64 + 4 * tx + (j - 4));
            float cn = cn_s[cl];
            int   kk = kc + cl;   // ascends with j within thread; strict < keeps earliest
            #pragma unroll
            for (int i = 0; i < 8; ++i) {
                int tl = (i < 4) ? (4 * ty + i) : (64 + 4 * ty + (i - 4));
                // s = fl(zn + cn); dist = fl(s - 2*acc). fmaf(-2,acc,s) equals
                // the two-step result because 2*acc is exact (power of two).
                float s = nofuse(zn_s[tl] + cn);
                float dist = fmaf(-2.0f, acc[i][j], s);
                if (dist < minv[i]) { minv[i] = dist; mini[i] = kk; }
            }
        }
    }

    // ---- argmin reduce across the 16 code-lanes of each token (shfl, no LDS) ----
    #pragma unroll
    for (int i = 0; i < 8; ++i) {
        float bv = minv[i];
        int   bi = mini[i];
        #pragma unroll
        for (int off = 1; off < 16; off <<= 1) {   // xor<16 stays in 16-lane group
            float ov = __shfl_xor(bv, off);
            int   oi = __shfl_xor(bi, off);
            if (ov < bv || (ov == bv && oi < bi)) { bv = ov; bi = oi; }
        }
        if (tx == 0) {
            int tl = (i < 4) ? (4 * ty + i) : (64 + 4 * ty + (i - 4));
            idx_out[t0 + tl]  = bi;
            idxf_out[t0 + tl] = (float)bi;
        }
    }
}

// ---------------- gather z_q + per-block loss partials ----------------
__global__ void gather_loss(const float* __restrict__ z, const float* __restrict__ cb,
                            const int* __restrict__ idx,
                            float* __restrict__ zq, float* __restrict__ partials) {
    int t = blockIdx.x * 2 + (threadIdx.x >> 7);
    int d = threadIdx.x & 127;
    int k = idx[t];
    float q  = cb[(size_t)k * DDIM + d];
    float zv = z[(size_t)t * DDIM + d];
    zq[(size_t)t * DDIM + d] = q;
    float diff = q - zv;
    float s = diff * diff;
    #pragma unroll
    for (int off = 32; off > 0; off >>= 1) s += __shfl_down(s, off);
    __shared__ float sm[4];
    int lane = threadIdx.x & 63, wv = threadIdx.x >> 6;
    if (lane == 0) sm[wv] = s;
    __syncthreads();
    if (threadIdx.x == 0) partials[blockIdx.x] = sm[0] + sm[1] + sm[2] + sm[3];
}

// ---------------- final loss reduce ----------------
__global__ void loss_final(const float* __restrict__ partials, float* __restrict__ out_loss) {
    double s = 0.0;
    for (int i = threadIdx.x; i < NTOK / 2; i += 256) s += (double)partials[i];
    #pragma unroll
    for (int off = 32; off > 0; off >>= 1) s += __shfl_down(s, off);
    __shared__ double sm[4];
    int lane = threadIdx.x & 63, wv = threadIdx.x >> 6;
    if (lane == 0) sm[wv] = s;
    __syncthreads();
    if (threadIdx.x == 0) {
        double tot = sm[0] + sm[1] + sm[2] + sm[3];
        // vq_loss = (1 + 0.25) * mean((q - z)^2)
        out_loss[0] = (float)(tot * 1.25 / (double)((size_t)NTOK * DDIM));
    }
}

extern "C" void kernel_launch(void* const* d_in, const int* in_sizes, int n_in,
                              void* d_out, int out_size, void* d_ws, size_t ws_size,
                              hipStream_t stream) {
    const float* z  = (const float*)d_in[0];   // [32768,128]
    const float* cb = (const float*)d_in[1];   // [1024,128]
    float* out = (float*)d_out;
    float* zq    = out;                        // 4194304
    float* loss  = out + (size_t)NTOK * DDIM;  // 1
    float* idxf  = loss + 1;                   // 32768 (indices as float)

    float* cnorm    = (float*)d_ws;                          // 1024 f
    int*   idx      = (int*)(cnorm + KCODES);                // 32768 i
    float* partials = (float*)(idx + NTOK);                  // 16384 f

    rownorm_np<<<KCODES / 256, 256, 0, stream>>>(cb, cnorm, KCODES);
    dist_argmin<<<NTOK / TT, 256, 0, stream>>>(z, cb, cnorm, idx, idxf);
    gather_loss<<<NTOK / 2, 256, 0, stream>>>(z, cb, idx, zq, partials);
    loss_final<<<1, 256, 0, stream>>>(partials, loss);
}

// Round 2
// 207.829 us; speedup vs baseline: 1.2477x; 1.2477x over previous
//
#include <hip/hip_runtime.h>
#include <float.h>

// Problem constants (fixed by reference): B=32 L=1024 D=128 K=1024
#define NTOK 32768
#define DDIM 128
#define KCODES 1024
#define TT 128    // tokens per block
#define KC 128    // codes per K-chunk
#define NCHUNK (KCODES / KC)
#define NTHR 512  // 8 waves -> 2 waves/SIMD at 1 block/CU

// Optimization barrier: prevents fma-contraction / reassociation across it,
// so we can replicate numpy's exact fp32 rounding sequence.
__device__ __forceinline__ float nofuse(float x) { asm volatile("" : "+v"(x)); return x; }

// numpy pairwise_sum for n=128 (its n<=PW_BLOCKSIZE path): 8 accumulators,
// r[j] = a[j] + a[8+j] + ... + a[120+j] (sequential), then
// ((r0+r1)+(r2+r3)) + ((r4+r5)+(r6+r7)). Squares rounded BEFORE adding
// (numpy computes z**2 elementwise first) — nofuse blocks fma fusion.
__global__ void rownorm_np(const float* __restrict__ a, float* __restrict__ out, int nrows) {
    int row = blockIdx.x * blockDim.x + threadIdx.x;
    if (row >= nrows) return;
    const float* p = a + (size_t)row * DDIM;
    float r[8];
    #pragma unroll
    for (int j = 0; j < 8; ++j) { float v = p[j]; r[j] = nofuse(v * v); }
    #pragma unroll
    for (int i = 8; i < DDIM; i += 8) {
        #pragma unroll
        for (int j = 0; j < 8; ++j) {
            float v = p[i + j];
            r[j] = nofuse(r[j] + nofuse(v * v));
        }
    }
    float s01 = nofuse(r[0] + r[1]);
    float s23 = nofuse(r[2] + r[3]);
    float s45 = nofuse(r[4] + r[5]);
    float s67 = nofuse(r[6] + r[7]);
    out[row] = nofuse(nofuse(s01 + s23) + nofuse(s45 + s67));
}

// ---------------- distances + argmin + gather + loss partials (fused) ----------------
// dist(t,k) = fl( fl(zn_t + cn_k) - 2*dot(z_t,c_k) )  — numpy fp32 semantics.
// 512 threads, 128x128 tile, per-thread 4 tokens x 8 codes (32 FMA / 3 ds_read_b128).
__global__ __launch_bounds__(NTHR, 2)
void dist_argmin(const float* __restrict__ z, const float* __restrict__ cb,
                 const float* __restrict__ cnorm,
                 float* __restrict__ zq, float* __restrict__ idxf_out,
                 float* __restrict__ partials) {
    // LDS: zt[DDIM][TT] | ct[DDIM][KC] | zn_s[TT] | cn_s[KC]   (132 KB, 1 block/CU)
    __shared__ float smem[DDIM * TT + DDIM * KC + TT + KC];
    float* zt   = smem;                    // [d][token], pitch TT
    float* ct   = smem + DDIM * TT;        // [d][code],  pitch KC
    float* zn_s = ct + DDIM * KC;          // [TT]
    float* cn_s = zn_s + TT;               // [KC]
    int*   bidx = (int*)ct;                // alias ct after the K-loop (post-barrier)

    const int tid = threadIdx.x;
    const int tx = tid & 15;   // code micro-col  (codes {4tx..4tx+3} U {64+4tx..})
    const int ty = tid >> 4;   // token micro-row (tokens 4ty..4ty+3), ty in 0..31
    const int t0 = blockIdx.x * TT;

    // ---- prefetch c-chunk 0 into registers (loads fly over z staging) ----
    float4 creg[8];
    #pragma unroll
    for (int it = 0; it < 8; ++it) {
        int g  = it * NTHR + tid;
        int c  = g & (KC - 1);
        int d4 = g >> 7;
        creg[it] = *(const float4*)(cb + (size_t)c * DDIM + 4 * d4);
    }
    float cnr = 0.0f;
    if (tid < KC) cnr = cnorm[tid];

    // ---- stage z-tile transposed: zt[d][t] ----
    #pragma unroll
    for (int it = 0; it < 8; ++it) {
        int g  = it * NTHR + tid;
        int t  = g & (TT - 1);
        int d4 = g >> 7;
        float4 v = *(const float4*)(z + (size_t)(t0 + t) * DDIM + 4 * d4);
        zt[(4 * d4 + 0) * TT + t] = v.x;
        zt[(4 * d4 + 1) * TT + t] = v.y;
        zt[(4 * d4 + 2) * TT + t] = v.z;
        zt[(4 * d4 + 3) * TT + t] = v.w;
    }
    __syncthreads();

    // ---- fused znorm: identical numpy pairwise sequence, fed from zt column ----
    if (tid < TT) {
        const float* col = zt + tid;   // col[d*TT] == z[t0+tid][d], exact copies
        float r[8];
        #pragma unroll
        for (int j = 0; j < 8; ++j) { float v = col[j * TT]; r[j] = nofuse(v * v); }
        #pragma unroll
        for (int i = 8; i < DDIM; i += 8) {
            #pragma unroll
            for (int j = 0; j < 8; ++j) {
                float v = col[(i + j) * TT];
                r[j] = nofuse(r[j] + nofuse(v * v));
            }
        }
        float s01 = nofuse(r[0] + r[1]);
        float s23 = nofuse(r[2] + r[3]);
        float s45 = nofuse(r[4] + r[5]);
        float s67 = nofuse(r[6] + r[7]);
        zn_s[tid] = nofuse(nofuse(s01 + s23) + nofuse(s45 + s67));
    }
    __syncthreads();

    // hoist this thread's 4 token norms into registers (constant across chunks)
    float znr[4];
    #pragma unroll
    for (int i = 0; i < 4; ++i) znr[i] = zn_s[4 * ty + i];

    float minv[4];
    int   mini[4];
    #pragma unroll
    for (int i = 0; i < 4; ++i) { minv[i] = FLT_MAX; mini[i] = 0; }

    for (int cc = 0; cc < NCHUNK; ++cc) {
        const int kc = cc * KC;
        __syncthreads();   // prev compute done reading ct/cn_s

        // write prefetched chunk to LDS (transposed)
        #pragma unroll
        for (int it = 0; it < 8; ++it) {
            int g  = it * NTHR + tid;
            int c  = g & (KC - 1);
            int d4 = g >> 7;
            float4 v = creg[it];
            ct[(4 * d4 + 0) * KC + c] = v.x;
            ct[(4 * d4 + 1) * KC + c] = v.y;
            ct[(4 * d4 + 2) * KC + c] = v.z;
            ct[(4 * d4 + 3) * KC + c] = v.w;
        }
        if (tid < KC) cn_s[tid] = cnr;
        __syncthreads();

        // prefetch next chunk (overlaps with the 128-step FMA phase below)
        if (cc + 1 < NCHUNK) {
            #pragma unroll
            for (int it = 0; it < 8; ++it) {
                int g  = it * NTHR + tid;
                int c  = g & (KC - 1);
                int d4 = g >> 7;
                creg[it] = *(const float4*)(cb + (size_t)(kc + KC + c) * DDIM + 4 * d4);
            }
            if (tid < KC) cnr = cnorm[kc + KC + tid];
        }

        float acc[4][8];
        #pragma unroll
        for (int i = 0; i < 4; ++i)
            #pragma unroll
            for (int j = 0; j < 8; ++j) acc[i][j] = 0.0f;

        #pragma unroll 4
        for (int d = 0; d < DDIM; ++d) {
            float4 a0 = *(const float4*)(zt + d * TT + 4 * ty);
            float4 b0 = *(const float4*)(ct + d * KC + 4 * tx);
            float4 b1 = *(const float4*)(ct + d * KC + 64 + 4 * tx);
            float ar[4] = {a0.x, a0.y, a0.z, a0.w};
            float br[8] = {b0.x, b0.y, b0.z, b0.w, b1.x, b1.y, b1.z, b1.w};
            #pragma unroll
            for (int i = 0; i < 4; ++i)
                #pragma unroll
                for (int j = 0; j < 8; ++j)
                    acc[i][j] = fmaf(ar[i], br[j], acc[i][j]);
        }

        #pragma unroll
        for (int j = 0; j < 8; ++j) {
            int cl = (j < 4) ? (4 * tx + j) : (64 + 4 * tx + (j - 4));
            float cn = cn_s[cl];
            int   kk = kc + cl;   // ascends with j within thread; strict < keeps earliest
            #pragma unroll
            for (int i = 0; i < 4; ++i) {
                // s = fl(zn + cn); dist = fl(s - 2*acc). fmaf(-2,acc,s) equals
                // the two-step result because 2*acc is exact (power of two).
                float s = nofuse(znr[i] + cn);
                float dist = fmaf(-2.0f, acc[i][j], s);
                if (dist < minv[i]) { minv[i] = dist; mini[i] = kk; }
            }
        }
    }

    // ---- argmin reduce across the 16 code-lanes of each token (shfl, no LDS) ----
    __syncthreads();   // all compute done; ct region reusable as bidx
    #pragma unroll
    for (int i = 0; i < 4; ++i) {
        float bv = minv[i];
        int   bi = mini[i];
        #pragma unroll
        for (int off = 1; off < 16; off <<= 1) {   // xor<16 stays in 16-lane group
            float ov = __shfl_xor(bv, off);
            int   oi = __shfl_xor(bi, off);
            if (ov < bv || (ov == bv && oi < bi)) { bv = ov; bi = oi; }
        }
        if (tx == 0) {
            int tl = 4 * ty + i;
            bidx[tl] = bi;
            idxf_out[t0 + tl] = (float)bi;
        }
    }
    __syncthreads();

    // ---- fused gather z_q + loss partial ----
    // 4096 float4 of output tile; g = ft*512+tid -> token g>>5, d4 g&31 (coalesced).
    // z re-read from global (L2-hot: this block streamed it moments ago);
    // zt column reads here would be a 32-way bank conflict, so don't use LDS.
    float s = 0.0f;
    #pragma unroll
    for (int ft = 0; ft < 8; ++ft) {
        int g  = ft * NTHR + tid;
        int t  = g >> 5;          // 0..127
        int d4 = g & 31;
        int k  = bidx[t];
        float4 q4 = *(const float4*)(cb + (size_t)k * DDIM + 4 * d4);
        float4 z4 = *(const float4*)(z + (size_t)(t0 + t) * DDIM + 4 * d4);
        *(float4*)(zq + (size_t)(t0 + t) * DDIM + 4 * d4) = q4;
        float dx = q4.x - z4.x, dy = q4.y - z4.y, dz = q4.z - z4.z, dw = q4.w - z4.w;
        s += dx * dx + dy * dy + dz * dz + dw * dw;
    }
    #pragma unroll
    for (int off = 32; off > 0; off >>= 1) s += __shfl_down(s, off);
    __shared__ float sm[8];
    int lane = tid & 63, wv = tid >> 6;
    if (lane == 0) sm[wv] = s;
    __syncthreads();
    if (tid == 0) {
        float tot = 0.0f;
        #pragma unroll
        for (int w = 0; w < 8; ++w) tot += sm[w];
        partials[blockIdx.x] = tot;
    }
}

// ---------------- final loss reduce ----------------
__global__ void loss_final(const float* __restrict__ partials, float* __restrict__ out_loss) {
    double s = 0.0;
    for (int i = threadIdx.x; i < NTOK / TT; i += 256) s += (double)partials[i];
    #pragma unroll
    for (int off = 32; off > 0; off >>= 1) s += __shfl_down(s, off);
    __shared__ double sm[4];
    int lane = threadIdx.x & 63, wv = threadIdx.x >> 6;
    if (lane == 0) sm[wv] = s;
    __syncthreads();
    if (threadIdx.x == 0) {
        double tot = sm[0] + sm[1] + sm[2] + sm[3];
        // vq_loss = (1 + 0.25) * mean((q - z)^2)
        out_loss[0] = (float)(tot * 1.25 / (double)((size_t)NTOK * DDIM));
    }
}

extern "C" void kernel_launch(void* const* d_in, const int* in_sizes, int n_in,
                              void* d_out, int out_size, void* d_ws, size_t ws_size,
                              hipStream_t stream) {
    const float* z  = (const float*)d_in[0];   // [32768,128]
    const float* cb = (const float*)d_in[1];   // [1024,128]
    float* out = (float*)d_out;
    float* zq    = out;                        // 4194304
    float* loss  = out + (size_t)NTOK * DDIM;  // 1
    float* idxf  = loss + 1;                   // 32768 (indices as float)

    float* cnorm    = (float*)d_ws;            // 1024 f
    float* partials = cnorm + KCODES;          // 256 f

    rownorm_np<<<KCODES / 256, 256, 0, stream>>>(cb, cnorm, KCODES);
    dist_argmin<<<NTOK / TT, NTHR, 0, stream>>>(z, cb, cnorm, zq, idxf, partials);
    loss_final<<<1, 256, 0, stream>>>(partials, loss);
}

// Round 3
// 131.724 us; speedup vs baseline: 1.9685x; 1.5778x over previous
//
#include <hip/hip_runtime.h>
#include <float.h>

// Problem constants (fixed by reference): B=32 L=1024 D=128 K=1024
#define NTOK 32768
#define DDIM 128
#define KCODES 1024
#define TT 128        // tokens per block
#define KC 64         // codes per chunk
#define NCHUNK (KCODES / KC)
#define NTHR 512      // 8 waves -> 2 waves/SIMD at 1 block/CU

typedef __attribute__((ext_vector_type(8))) short short8v;   // 8 bf16 (4 VGPRs)
typedef __attribute__((ext_vector_type(4))) float f32x4;     // mfma accumulator

// Optimization barrier: prevents fma-contraction / reassociation across it,
// so we can replicate numpy's exact fp32 rounding sequence.
__device__ __forceinline__ float nofuse(float x) { asm volatile("" : "+v"(x)); return x; }

// bf16 round-to-nearest-even (finite data only)
__device__ __forceinline__ unsigned short bf16rne(float x) {
    unsigned int u = __float_as_uint(x);
    unsigned int r = u + 0x7FFFu + ((u >> 16) & 1u);
    return (unsigned short)(r >> 16);
}
__device__ __forceinline__ float bf16tof(unsigned short h) {
    return __uint_as_float(((unsigned int)h) << 16);
}

// split 8 floats into bf16 hi/lo packed words (2 bf16 per uint, d-ascending)
__device__ __forceinline__ void cvt8(const float* f, uint4& hw, uint4& lw) {
    unsigned int h[8], l[8];
    #pragma unroll
    for (int e = 0; e < 8; ++e) {
        unsigned short hh = bf16rne(f[e]);
        unsigned short ll = bf16rne(f[e] - bf16tof(hh));
        h[e] = hh; l[e] = ll;
    }
    hw = make_uint4(h[0] | (h[1] << 16), h[2] | (h[3] << 16),
                    h[4] | (h[5] << 16), h[6] | (h[7] << 16));
    lw = make_uint4(l[0] | (l[1] << 16), l[2] | (l[3] << 16),
                    l[4] | (l[5] << 16), l[6] | (l[7] << 16));
}

// numpy pairwise_sum for n=128: 8 accumulators, squares rounded before adding.
__global__ void rownorm_np(const float* __restrict__ a, float* __restrict__ out, int nrows) {
    int row = blockIdx.x * blockDim.x + threadIdx.x;
    if (row >= nrows) return;
    const float* p = a + (size_t)row * DDIM;
    float r[8];
    #pragma unroll
    for (int j = 0; j < 8; ++j) { float v = p[j]; r[j] = nofuse(v * v); }
    #pragma unroll
    for (int i = 8; i < DDIM; i += 8) {
        #pragma unroll
        for (int j = 0; j < 8; ++j) {
            float v = p[i + j];
            r[j] = nofuse(r[j] + nofuse(v * v));
        }
    }
    float s01 = nofuse(r[0] + r[1]);
    float s23 = nofuse(r[2] + r[3]);
    float s45 = nofuse(r[4] + r[5]);
    float s67 = nofuse(r[6] + r[7]);
    out[row] = nofuse(nofuse(s01 + s23) + nofuse(s45 + s67));
}

// ---------------- distances (split-bf16 MFMA) + argmin + gather + loss ----------------
// dot(z,c) = ah*bh + ah*bl + al*bh accumulated in fp32 by mfma_f32_16x16x32_bf16
// (al*bl dropped: ~2^-18 relative). dist = fl( fl(zn+cn) - 2*acc ) as before.
__global__ __launch_bounds__(NTHR, 2)
void dist_argmin(const float* __restrict__ z, const float* __restrict__ cb,
                 const float* __restrict__ cnorm,
                 float* __restrict__ zq, float* __restrict__ idxf_out,
                 float* __restrict__ partials) {
    // LDS (bytes): ztH 32768 | ztL 32768 | ctH 16384 | ctL 16384 | zn 512 = 98816
    __shared__ __align__(16) char smem[2 * 32768 + 2 * 16384 + 512];
    char* ztH = smem;                   // [128 tok][128 d] bf16 hi, XOR-swizzled rows
    char* ztL = smem + 32768;
    char* ctH = smem + 65536;           // [64 code][128 d] bf16 hi, XOR-swizzled rows
    char* ctL = smem + 65536 + 16384;
    float* zn_s = (float*)(smem + 65536 + 32768);   // [128]
    // post-loop aliases (inside ctH, after final barrier)
    float* red_v = (float*)ctH;                     // [128][2]
    int*   red_i = (int*)(ctH + 2048);              // [128][2]
    int*   bidx  = (int*)(ctH + 4096);              // [128]

    const int tid  = threadIdx.x;
    const int lane = tid & 63;
    const int wave = tid >> 6;     // 0..7
    const int wy   = wave & 3;     // token group: 32 tokens
    const int wx   = wave >> 2;    // code group: 32 codes per chunk
    const int l15  = lane & 15;
    const int l4   = lane >> 4;    // 0..3
    const int t0   = blockIdx.x * TT;

    // ---- prefetch cb chunk 0 (fp32) into regs; loads fly over z staging ----
    float4 pf[4];
    #pragma unroll
    for (int it = 0; it < 2; ++it) {
        int gd = it * NTHR + tid;
        int row = gd >> 4, slot = gd & 15;
        const float* g = cb + (size_t)row * DDIM + slot * 8;
        pf[2 * it]     = *(const float4*)g;
        pf[2 * it + 1] = *(const float4*)(g + 4);
    }

    // ---- stage z tile -> bf16 hi/lo, [token][d], row-XOR swizzle ----
    #pragma unroll
    for (int it = 0; it < 4; ++it) {
        int g = it * NTHR + tid;
        int row = g >> 4, d8 = g & 15;
        const float* p = z + (size_t)(t0 + row) * DDIM + d8 * 8;
        float4 a = *(const float4*)p;
        float4 b = *(const float4*)(p + 4);
        float f[8] = {a.x, a.y, a.z, a.w, b.x, b.y, b.z, b.w};
        uint4 hw, lw;
        cvt8(f, hw, lw);
        int off = row * 256 + ((d8 << 4) ^ ((row & 7) << 4));
        *(uint4*)(ztH + off) = hw;
        *(uint4*)(ztL + off) = lw;
    }

    // ---- znorm: exact numpy pairwise sequence from global fp32 (L1/L2-hot) ----
    if (tid < TT) {
        const float* p = z + (size_t)(t0 + tid) * DDIM;
        float r[8];
        {
            float4 a = *(const float4*)p, b = *(const float4*)(p + 4);
            float v[8] = {a.x, a.y, a.z, a.w, b.x, b.y, b.z, b.w};
            #pragma unroll
            for (int j = 0; j < 8; ++j) r[j] = nofuse(v[j] * v[j]);
        }
        #pragma unroll
        for (int i = 8; i < DDIM; i += 8) {
            float4 a = *(const float4*)(p + i), b = *(const float4*)(p + i + 4);
            float v[8] = {a.x, a.y, a.z, a.w, b.x, b.y, b.z, b.w};
            #pragma unroll
            for (int j = 0; j < 8; ++j) r[j] = nofuse(r[j] + nofuse(v[j] * v[j]));
        }
        float s01 = nofuse(r[0] + r[1]), s23 = nofuse(r[2] + r[3]);
        float s45 = nofuse(r[4] + r[5]), s67 = nofuse(r[6] + r[7]);
        zn_s[tid] = nofuse(nofuse(s01 + s23) + nofuse(s45 + s67));
    }
    __syncthreads();

    // ---- A-fragments (z) register-resident for ALL chunks: 16 frags = 64 VGPR ----
    // mfma A layout: lane holds A[m = lane&15][k = (lane>>4)*8 + j]
    short8v Ah[2][4], Al[2][4];
    #pragma unroll
    for (int tf = 0; tf < 2; ++tf) {
        int row = wy * 32 + tf * 16 + l15;
        int swz = (row & 7) << 4;
        #pragma unroll
        for (int ks = 0; ks < 4; ++ks) {
            int off = row * 256 + ((ks * 64 + (l4 << 4)) ^ swz);
            Ah[tf][ks] = *(const short8v*)(ztH + off);
            Al[tf][ks] = *(const short8v*)(ztL + off);
        }
    }
    float znr[8];
    #pragma unroll
    for (int tf = 0; tf < 2; ++tf)
        #pragma unroll
        for (int rg = 0; rg < 4; ++rg)
            znr[tf * 4 + rg] = zn_s[wy * 32 + tf * 16 + l4 * 4 + rg];

    float minv[8]; int mini[8];
    #pragma unroll
    for (int i = 0; i < 8; ++i) { minv[i] = FLT_MAX; mini[i] = 0; }

    for (int cc = 0; cc < NCHUNK; ++cc) {
        const int kc = cc * KC;
        __syncthreads();   // previous compute done reading ct
        // write prefetched chunk: cvt fp32 -> bf16 hi/lo, [code][d], swizzled
        #pragma unroll
        for (int it = 0; it < 2; ++it) {
            int gd = it * NTHR + tid;
            int row = gd >> 4, slot = gd & 15;
            float f[8] = {pf[2*it].x, pf[2*it].y, pf[2*it].z, pf[2*it].w,
                          pf[2*it+1].x, pf[2*it+1].y, pf[2*it+1].z, pf[2*it+1].w};
            uint4 hw, lw;
            cvt8(f, hw, lw);
            int off = row * 256 + ((slot << 4) ^ ((row & 7) << 4));
            *(uint4*)(ctH + off) = hw;
            *(uint4*)(ctL + off) = lw;
        }
        __syncthreads();
        // prefetch next chunk (overlaps the MFMA phase below)
        if (cc + 1 < NCHUNK) {
            #pragma unroll
            for (int it = 0; it < 2; ++it) {
                int gd = it * NTHR + tid;
                int row = gd >> 4, slot = gd & 15;
                const float* g = cb + (size_t)(kc + KC + row) * DDIM + slot * 8;
                pf[2 * it]     = *(const float4*)g;
                pf[2 * it + 1] = *(const float4*)(g + 4);
            }
        }

        f32x4 acc[2][2];
        #pragma unroll
        for (int tf = 0; tf < 2; ++tf)
            #pragma unroll
            for (int cf = 0; cf < 2; ++cf)
                acc[tf][cf] = (f32x4){0.f, 0.f, 0.f, 0.f};

        #pragma unroll
        for (int ks = 0; ks < 4; ++ks) {
            short8v Bh[2], Bl[2];
            #pragma unroll
            for (int cf = 0; cf < 2; ++cf) {
                int row = wx * 32 + cf * 16 + l15;
                int off = row * 256 + ((ks * 64 + (l4 << 4)) ^ ((row & 7) << 4));
                Bh[cf] = *(const short8v*)(ctH + off);
                Bl[cf] = *(const short8v*)(ctL + off);
            }
            #pragma unroll
            for (int tf = 0; tf < 2; ++tf)
                #pragma unroll
                for (int cf = 0; cf < 2; ++cf) {
                    acc[tf][cf] = __builtin_amdgcn_mfma_f32_16x16x32_bf16(Ah[tf][ks], Bh[cf], acc[tf][cf], 0, 0, 0);
                    acc[tf][cf] = __builtin_amdgcn_mfma_f32_16x16x32_bf16(Ah[tf][ks], Bl[cf], acc[tf][cf], 0, 0, 0);
                    acc[tf][cf] = __builtin_amdgcn_mfma_f32_16x16x32_bf16(Al[tf][ks], Bh[cf], acc[tf][cf], 0, 0, 0);
                }
        }

        // epilogue: C/D layout col=lane&15, row=(lane>>4)*4+reg (verified m89)
        #pragma unroll
        for (int cf = 0; cf < 2; ++cf) {
            int kk = kc + wx * 32 + cf * 16 + l15;   // ascends with cf, then cc
            float cn = cnorm[kk];                     // 4 KB array, L1-hot
            #pragma unroll
            for (int tf = 0; tf < 2; ++tf)
                #pragma unroll
                for (int rg = 0; rg < 4; ++rg) {
                    // s = fl(zn + cn); dist = fl(s - 2*acc); 2*acc exact (pow2)
                    float s = nofuse(znr[tf * 4 + rg] + cn);
                    float dist = fmaf(-2.0f, acc[tf][cf][rg], s);
                    int ii = tf * 4 + rg;
                    if (dist < minv[ii]) { minv[ii] = dist; mini[ii] = kk; }
                }
        }
    }

    // ---- argmin reduce: butterfly over the 16 code-lanes, then across 2 wx waves ----
    __syncthreads();   // ct dead; red arrays alias it
    #pragma unroll
    for (int i = 0; i < 8; ++i) {
        float bv = minv[i]; int bi = mini[i];
        #pragma unroll
        for (int off = 1; off < 16; off <<= 1) {   // xor<16 stays in 16-lane group
            float ov = __shfl_xor(bv, off);
            int   oi = __shfl_xor(bi, off);
            if (ov < bv || (ov == bv && oi < bi)) { bv = ov; bi = oi; }
        }
        if (l15 == 0) {
            int tok = wy * 32 + (i >> 2) * 16 + l4 * 4 + (i & 3);
            red_v[tok * 2 + wx] = bv;
            red_i[tok * 2 + wx] = bi;
        }
    }
    __syncthreads();
    if (tid < TT) {
        float bv = red_v[tid * 2]; int bi = red_i[tid * 2];
        float v1 = red_v[tid * 2 + 1]; int i1 = red_i[tid * 2 + 1];
        if (v1 < bv || (v1 == bv && i1 < bi)) { bv = v1; bi = i1; }
        bidx[tid] = bi;
        idxf_out[t0 + tid] = (float)bi;
    }
    __syncthreads();

    // ---- fused gather z_q + loss partial (fp32 exact copies from cb) ----
    float s = 0.0f;
    #pragma unroll
    for (int ft = 0; ft < 8; ++ft) {
        int g = ft * NTHR + tid;
        int t = g >> 5;          // 0..127
        int d4 = g & 31;
        int k = bidx[t];
        float4 q4 = *(const float4*)(cb + (size_t)k * DDIM + 4 * d4);
        float4 z4 = *(const float4*)(z + (size_t)(t0 + t) * DDIM + 4 * d4);
        *(float4*)(zq + (size_t)(t0 + t) * DDIM + 4 * d4) = q4;
        float dx = q4.x - z4.x, dy = q4.y - z4.y, dz = q4.z - z4.z, dw = q4.w - z4.w;
        s += dx * dx + dy * dy + dz * dz + dw * dw;
    }
    #pragma unroll
    for (int off = 32; off > 0; off >>= 1) s += __shfl_down(s, off);
    __shared__ float sm[8];
    if ((tid & 63) == 0) sm[tid >> 6] = s;
    __syncthreads();
    if (tid == 0) {
        float tot = 0.0f;
        #pragma unroll
        for (int w = 0; w < 8; ++w) tot += sm[w];
        partials[blockIdx.x] = tot;
    }
}

// ---------------- final loss reduce ----------------
__global__ void loss_final(const float* __restrict__ partials, float* __restrict__ out_loss) {
    double s = 0.0;
    for (int i = threadIdx.x; i < NTOK / TT; i += 256) s += (double)partials[i];
    #pragma unroll
    for (int off = 32; off > 0; off >>= 1) s += __shfl_down(s, off);
    __shared__ double sm[4];
    int lane = threadIdx.x & 63, wv = threadIdx.x >> 6;
    if (lane == 0) sm[wv] = s;
    __syncthreads();
    if (threadIdx.x == 0) {
        double tot = sm[0] + sm[1] + sm[2] + sm[3];
        // vq_loss = (1 + 0.25) * mean((q - z)^2)
        out_loss[0] = (float)(tot * 1.25 / (double)((size_t)NTOK * DDIM));
    }
}

extern "C" void kernel_launch(void* const* d_in, const int* in_sizes, int n_in,
                              void* d_out, int out_size, void* d_ws, size_t ws_size,
                              hipStream_t stream) {
    const float* z  = (const float*)d_in[0];   // [32768,128]
    const float* cb = (const float*)d_in[1];   // [1024,128]
    float* out = (float*)d_out;
    float* zq   = out;                         // 4194304
    float* loss = out + (size_t)NTOK * DDIM;   // 1
    float* idxf = loss + 1;                    // 32768 (indices as float)

    float* cnorm    = (float*)d_ws;            // 1024 f
    float* partials = cnorm + KCODES;          // 256 f

    rownorm_np<<<KCODES / 256, 256, 0, stream>>>(cb, cnorm, KCODES);
    dist_argmin<<<NTOK / TT, NTHR, 0, stream>>>(z, cb, cnorm, zq, idxf, partials);
    loss_final<<<1, 256, 0, stream>>>(partials, loss);
}